// Round 1
// baseline (245.151 us; speedup 1.0000x reference)
//
#include <hip/hip_runtime.h>

#define TAU 8e-3f

typedef __attribute__((ext_vector_type(8))) short bf16x8;
typedef __attribute__((ext_vector_type(4))) float f32x4;
typedef __attribute__((ext_vector_type(4))) unsigned int u32x4;

// ws layout: Wswz[4*64*64*8 u16 = 256 KB] | accum[512 f32] | counter[u32]
#define ACCUM_OFF 262144

// round-to-nearest-even fp32 -> bf16 (as u16)
#define RNE16(f) \
  ((unsigned short)((__float_as_uint(f) + 0x7fffu + ((__float_as_uint(f) >> 16) & 1u)) >> 16))

// ---- kernel 0: W fp32 -> bf16, swizzled to MFMA-fragment-linear ----------
// Wswz[g][ks][lane] (8 u16 each): lane(fm,kg) holds W[g*16+fm][ks*32+kg*8 .. +8]
__global__ __launch_bounds__(256) void wconv(const float* __restrict__ W,
                                             unsigned short* __restrict__ Wswz,
                                             float* __restrict__ accum) {
  int t = blockIdx.x * 256 + threadIdx.x;  // 64 blocks -> 16384 threads
  int g = t >> 12, rem = t & 4095;
  int ks = rem >> 6, lane = rem & 63;
  int fm = lane & 15, kg = lane >> 4;
  const float* src = W + (size_t)(g * 16 + fm) * 2048 + ks * 32 + kg * 8;
  float4 a = *(const float4*)src;
  float4 b = *(const float4*)(src + 4);
  ushort4 lo = make_ushort4(RNE16(a.x), RNE16(a.y), RNE16(a.z), RNE16(a.w));
  ushort4 hi = make_ushort4(RNE16(b.x), RNE16(b.y), RNE16(b.z), RNE16(b.w));
  unsigned short* dst = Wswz + (size_t)t * 8;
  *(ushort4*)dst = lo;
  *(ushort4*)(dst + 4) = hi;
  if (blockIdx.x == 0) {
    accum[threadIdx.x] = 0.f;
    accum[256 + threadIdx.x] = 0.f;
    if (threadIdx.x == 0) ((unsigned*)accum)[512] = 0u;
  }
}

#define CVTPK(dst, a, b) \
  asm("v_cvt_pk_bf16_f32 %0, %1, %2" : "=v"(dst) : "v"(a), "v"(b))

// ---- kernel 1: main gate --------------------------------------------------
// 256 blocks x 512 threads (8 waves = 4 wave-pairs). Pair p: 16 tokens.
// Half h of a pair: K in [h*1024, h*1024+1024), 32 iters of K=32.
// x prefetch depth 2, W-fragment prefetch depth 1 (manual register pipeline).
__global__ __launch_bounds__(512, 2) void gate_main(
    const float* __restrict__ x, const float* __restrict__ Wf,
    const unsigned short* __restrict__ Wswz,
    float* __restrict__ out, float* __restrict__ accum) {
  __shared__ float part[4][16][68];  // pitch 68: 2-way banks (free); cols 64..67 = scratch

  const int tid = threadIdx.x;
  const int lane = tid & 63;
  const int w = __builtin_amdgcn_readfirstlane(tid >> 6);
  const int p = w >> 1;   // wave-pair 0..3
  const int h = w & 1;    // K-half
  const int fm = lane & 15;
  const int kg = lane >> 4;
  const int tokp = blockIdx.x * 64 + p * 16;

  const float* xr = x + (size_t)(tokp + fm) * 2048 + h * 1024 + kg * 8;
  const bf16x8* wsw = (const bf16x8*)Wswz + lane;  // + (g*64+ks)*64
  const int ks0 = h * 32;

  f32x4 acc[4];
#pragma unroll
  for (int g = 0; g < 4; ++g) acc[g] = (f32x4){0.f, 0.f, 0.f, 0.f};

  // prime the pipeline: x iters 0,1; W iter 0
  float4 xa0 = *(const float4*)(xr);
  float4 xa1 = *(const float4*)(xr + 4);
  float4 xb0 = *(const float4*)(xr + 32);
  float4 xb1 = *(const float4*)(xr + 36);
  bf16x8 w0 = wsw[(0 * 64 + ks0) * 64];
  bf16x8 w1 = wsw[(1 * 64 + ks0) * 64];
  bf16x8 w2 = wsw[(2 * 64 + ks0) * 64];
  bf16x8 w3 = wsw[(3 * 64 + ks0) * 64];

#pragma unroll
  for (int it = 0; it < 32; ++it) {
    float4 xn0 = {}, xn1 = {};
    bf16x8 n0 = {}, n1 = {}, n2 = {}, n3 = {};
    if (it < 30) {  // issue x loads 2 iterations ahead
      xn0 = *(const float4*)(xr + (it + 2) * 32);
      xn1 = *(const float4*)(xr + (it + 2) * 32 + 4);
    }
    if (it < 31) {  // issue W loads 1 iteration ahead (L2-resident)
      const int ks = ks0 + it + 1;
      n0 = wsw[(0 * 64 + ks) * 64];
      n1 = wsw[(1 * 64 + ks) * 64];
      n2 = wsw[(2 * 64 + ks) * 64];
      n3 = wsw[(3 * 64 + ks) * 64];
    }
    unsigned u0, u1, u2, u3;
    CVTPK(u0, xa0.x, xa0.y);
    CVTPK(u1, xa0.z, xa0.w);
    CVTPK(u2, xa1.x, xa1.y);
    CVTPK(u3, xa1.z, xa1.w);
    u32x4 uu = (u32x4){u0, u1, u2, u3};
    bf16x8 a = __builtin_bit_cast(bf16x8, uu);
    acc[0] = __builtin_amdgcn_mfma_f32_16x16x32_bf16(a, w0, acc[0], 0, 0, 0);
    acc[1] = __builtin_amdgcn_mfma_f32_16x16x32_bf16(a, w1, acc[1], 0, 0, 0);
    acc[2] = __builtin_amdgcn_mfma_f32_16x16x32_bf16(a, w2, acc[2], 0, 0, 0);
    acc[3] = __builtin_amdgcn_mfma_f32_16x16x32_bf16(a, w3, acc[3], 0, 0, 0);
    // rotate pipeline registers (renamed by compiler, no moves)
    xa0 = xb0; xa1 = xb1; xb0 = xn0; xb1 = xn1;
    w0 = n0; w1 = n1; w2 = n2; w3 = n3;
  }

  // ---- K-half reduction: odd wave stages, even wave merges ----------------
  // C-layout: token = kg*4 + r, expert = g*16 + fm
  if (h) {
#pragma unroll
    for (int g = 0; g < 4; ++g)
#pragma unroll
      for (int r = 0; r < 4; ++r)
        part[p][kg * 4 + r][g * 16 + fm] = acc[g][r];
  }
  __syncthreads();
  if (h) return;  // even waves do the epilogue; no further barriers

#pragma unroll
  for (int g = 0; g < 4; ++g)
#pragma unroll
    for (int r = 0; r < 4; ++r)
      part[p][kg * 4 + r][g * 16 + fm] += acc[g][r];

  // ---- per-token top-3 scan (lanes 0..15, token = lane) -------------------
  const int t = lane;
  float m1 = -3e38f, m2 = -3e38f, m3 = -3e38f;
  int i1 = 0, i2 = 0;
  if (lane < 16) {
    for (int e = 0; e < 64; ++e) {
      float v = part[p][t][e];
      if (v > m1) { m3 = m2; m2 = m1; i2 = i1; m1 = v; i1 = e; }
      else if (v > m2) { m3 = m2; m2 = v; i2 = e; }
      else if (v > m3) { m3 = v; }
    }
    part[p][t][64] = m2;  // threshold scratch
  }
  bool flg = (lane < 16) && ((m1 - m2 < TAU) || (m2 - m3 < TAU));
  unsigned long long msk = __ballot(flg);

  // exact fp32 re-dot for near-tie tokens: whole wave, K split over lanes
  while (msk) {
    int tt = __ffsll(msk) - 1;
    msk &= msk - 1;
    float thr = part[p][tt][64] - TAU;
    unsigned long long cand = __ballot(part[p][tt][lane] >= thr);
    const float* xr2 = x + (size_t)(tokp + tt) * 2048 + lane * 32;
    while (cand) {
      int e = __ffsll(cand) - 1;
      cand &= cand - 1;
      const float* wr = Wf + (size_t)e * 2048 + lane * 32;
      float s = 0.f;
#pragma unroll
      for (int kk = 0; kk < 32; kk += 8) {
        float4 uu0 = *(const float4*)(xr2 + kk);
        float4 vv0 = *(const float4*)(wr + kk);
        float4 uu1 = *(const float4*)(xr2 + kk + 4);
        float4 vv1 = *(const float4*)(wr + kk + 4);
        s += uu0.x * vv0.x + uu0.y * vv0.y + uu0.z * vv0.z + uu0.w * vv0.w +
             uu1.x * vv1.x + uu1.y * vv1.y + uu1.z * vv1.z + uu1.w * vv1.w;
      }
      for (int o = 32; o; o >>= 1) s += __shfl_xor(s, o, 64);
      if (lane == 0) part[p][tt][e] = s;
    }
  }

  // ---- final top-2 + softmax + outputs (lanes 0..15) ----------------------
  if (lane < 16) {
    m1 = -3e38f; m2 = -3e38f; i1 = 0; i2 = 0;
    for (int e = 0; e < 64; ++e) {
      float v = part[p][t][e];
      if (v > m1) { m2 = m1; i2 = i1; m1 = v; i1 = e; }
      else if (v > m2) { m2 = v; i2 = e; }
    }
    float Z = 0.f;
    for (int e = 0; e < 64; ++e) Z += __expf(part[p][t][e] - m1);
    float iz = 1.f / Z;
    float p1 = iz;
    float p2 = __expf(m2 - m1) * iz;
    float dn = 1.f / (p1 + p2 + 1e-20f);
    size_t tg = (size_t)(tokp + t);
    out[tg * 2 + 0] = (float)i1;
    out[tg * 2 + 1] = (float)i2;
    out[32768 + tg * 2 + 0] = p1 * dn;
    out[32768 + tg * 2 + 1] = p2 * dn;
    part[p][t][64] = m1;
    part[p][t][65] = iz;
    part[p][t][66] = __int_as_float(i1);
    part[p][t][67] = __int_as_float(i2);
  }

  // ---- per-(batch,expert) softmax sums + top2 counts (lane = expert) ------
  const int b = blockIdx.x >> 6;  // 64 blocks per batch row
  float ssum = 0.f;
  int cnt = 0;
#pragma unroll
  for (int t2 = 0; t2 < 16; ++t2) {
    float m1t = part[p][t2][64];
    float izt = part[p][t2][65];
    int i1t = __float_as_int(part[p][t2][66]);
    int i2t = __float_as_int(part[p][t2][67]);
    ssum += __expf(part[p][t2][lane] - m1t) * izt;
    cnt += (i1t == lane) + (i2t == lane);
  }
  atomicAdd(&accum[b * 64 + lane], ssum);
  atomicAdd(&accum[256 + b * 64 + lane], (float)cnt);

  // last epilogue wave (of 1024) finalizes aux loss
  __threadfence();
  unsigned old = 0;
  if (lane == 0) old = atomicAdd((unsigned*)accum + 512, 1u);
  old = (unsigned)__shfl((int)old, 0, 64);
  if (old == 1023u) {
    __threadfence();
    float tot = 0.f;
#pragma unroll
    for (int bb = 0; bb < 4; ++bb) {
      float ss = atomicAdd(&accum[bb * 64 + lane], 0.f);
      float cc = atomicAdd(&accum[256 + bb * 64 + lane], 0.f);
      tot += cc * (1.f / 128.f) * (ss * (1.f / 4096.f));
    }
    for (int o = 32; o; o >>= 1) tot += __shfl_xor(tot, o, 64);
    if (lane == 0) out[65536] = 0.025f * tot;  // alpha/B = 0.1/4
  }
}

extern "C" void kernel_launch(void* const* d_in, const int* in_sizes, int n_in,
                              void* d_out, int out_size, void* d_ws, size_t ws_size,
                              hipStream_t stream) {
  const float* x = (const float*)d_in[0];
  const float* Wf = (const float*)d_in[1];
  float* out = (float*)d_out;
  unsigned short* Wswz = (unsigned short*)d_ws;
  float* accum = (float*)((char*)d_ws + ACCUM_OFF);
  wconv<<<64, 256, 0, stream>>>(Wf, Wswz, accum);
  gate_main<<<256, 512, 0, stream>>>(x, Wf, Wswz, out, accum);
}

// Round 2
// 221.674 us; speedup vs baseline: 1.1059x; 1.1059x over previous
//
#include <hip/hip_runtime.h>

#define TAU 8e-3f

typedef __attribute__((ext_vector_type(8))) short bf16x8;
typedef __attribute__((ext_vector_type(4))) float f32x4;
typedef __attribute__((ext_vector_type(4))) unsigned int u32x4;

// ws layout: Wswz[4*64*64*8 u16 = 256 KB] | logits[16384*64 f32 = 4 MB] | accum[512 f32] | counter[u32]
#define LOGITS_OFF 262144
#define ACCUM_OFF (262144 + 4194304)

// round-to-nearest-even fp32 -> bf16 (as u16)
#define RNE16(f) \
  ((unsigned short)((__float_as_uint(f) + 0x7fffu + ((__float_as_uint(f) >> 16) & 1u)) >> 16))

#define CVTPK(dst, a, b) \
  asm("v_cvt_pk_bf16_f32 %0, %1, %2" : "=v"(dst) : "v"(a), "v"(b))

// ---- kernel 0: W fp32 -> bf16, swizzled to MFMA-fragment-linear ----------
// Wswz[g][ks][lane] (8 u16 each): lane(fm,kg) holds W[g*16+fm][ks*32+kg*8 .. +8]
__global__ __launch_bounds__(256) void wconv(const float* __restrict__ W,
                                             unsigned short* __restrict__ Wswz,
                                             float* __restrict__ accum) {
  int t = blockIdx.x * 256 + threadIdx.x;  // 64 blocks -> 16384 threads
  int g = t >> 12, rem = t & 4095;
  int ks = rem >> 6, lane = rem & 63;
  int fm = lane & 15, kg = lane >> 4;
  const float* src = W + (size_t)(g * 16 + fm) * 2048 + ks * 32 + kg * 8;
  float4 a = *(const float4*)src;
  float4 b = *(const float4*)(src + 4);
  ushort4 lo = make_ushort4(RNE16(a.x), RNE16(a.y), RNE16(a.z), RNE16(a.w));
  ushort4 hi = make_ushort4(RNE16(b.x), RNE16(b.y), RNE16(b.z), RNE16(b.w));
  unsigned short* dst = Wswz + (size_t)t * 8;
  *(ushort4*)dst = lo;
  *(ushort4*)(dst + 4) = hi;
  if (blockIdx.x == 0) {
    accum[threadIdx.x] = 0.f;
    accum[256 + threadIdx.x] = 0.f;
    if (threadIdx.x == 0) ((unsigned*)accum)[512] = 0u;
  }
}

// ---- kernel 1: GEMM only --------------------------------------------------
// 1024 blocks x 512 threads (8 waves). Block: 16 tokens, all 64 experts.
// Wave w: K-eighth [w*256, w*256+256). Writes fp32 logits to workspace.
// LDS 34816 B -> 4 blocks/CU -> 32 waves/CU.
__global__ __launch_bounds__(512, 8) void gate_gemm(
    const float* __restrict__ x, const unsigned short* __restrict__ Wswz,
    float* __restrict__ logits) {
  __shared__ float part[8][16][68];  // pitch 68: 2-way banks (free)

  const int tid = threadIdx.x;
  const int lane = tid & 63;
  const int w = __builtin_amdgcn_readfirstlane(tid >> 6);  // K-eighth 0..7
  const int fm = lane & 15;
  const int kg = lane >> 4;
  const int tok0 = blockIdx.x * 16;

  const float* xr = x + (size_t)(tok0 + fm) * 2048 + w * 256 + kg * 8;
  const bf16x8* wsw = (const bf16x8*)Wswz + lane;  // + (g*64+ks)*64

  f32x4 acc[4];
#pragma unroll
  for (int g = 0; g < 4; ++g) acc[g] = (f32x4){0.f, 0.f, 0.f, 0.f};

#pragma unroll
  for (int it = 0; it < 8; ++it) {
    const int ks = w * 8 + it;
    float4 p0 = *(const float4*)(xr + it * 32);
    float4 p1 = *(const float4*)(xr + it * 32 + 4);
    bf16x8 b0 = wsw[(0 * 64 + ks) * 64];
    bf16x8 b1 = wsw[(1 * 64 + ks) * 64];
    bf16x8 b2 = wsw[(2 * 64 + ks) * 64];
    bf16x8 b3 = wsw[(3 * 64 + ks) * 64];
    unsigned u0, u1, u2, u3;
    CVTPK(u0, p0.x, p0.y);
    CVTPK(u1, p0.z, p0.w);
    CVTPK(u2, p1.x, p1.y);
    CVTPK(u3, p1.z, p1.w);
    u32x4 uu = (u32x4){u0, u1, u2, u3};
    bf16x8 a = __builtin_bit_cast(bf16x8, uu);
    acc[0] = __builtin_amdgcn_mfma_f32_16x16x32_bf16(a, b0, acc[0], 0, 0, 0);
    acc[1] = __builtin_amdgcn_mfma_f32_16x16x32_bf16(a, b1, acc[1], 0, 0, 0);
    acc[2] = __builtin_amdgcn_mfma_f32_16x16x32_bf16(a, b2, acc[2], 0, 0, 0);
    acc[3] = __builtin_amdgcn_mfma_f32_16x16x32_bf16(a, b3, acc[3], 0, 0, 0);
  }

  // C-layout: token = kg*4 + r, expert = g*16 + fm
#pragma unroll
  for (int g = 0; g < 4; ++g)
#pragma unroll
    for (int r = 0; r < 4; ++r)
      part[w][kg * 4 + r][g * 16 + fm] = acc[g][r];
  __syncthreads();

  // reduce 8 K-eighths: 1024 cells over 512 threads, write coalesced
#pragma unroll
  for (int p = tid; p < 1024; p += 512) {
    int t = p >> 6, e = p & 63;
    float s = part[0][t][e];
#pragma unroll
    for (int ww = 1; ww < 8; ++ww) s += part[ww][t][e];
    logits[(size_t)(tok0 + t) * 64 + e] = s;
  }
}

// ---- kernel 2: wave-parallel epilogue ------------------------------------
// 256 blocks x 1024 threads (16 waves). Block: 64 tokens; wave: 4 tokens.
// lane = expert. All reductions via shfl butterflies (no serial lane scans).
__global__ __launch_bounds__(1024) void gate_top(
    const float* __restrict__ x, const float* __restrict__ Wf,
    const float* __restrict__ logits, float* __restrict__ out,
    float* __restrict__ accum) {
  __shared__ float sm[16][64];
  __shared__ float cn[16][64];

  const int tid = threadIdx.x;
  const int lane = tid & 63;
  const int w = tid >> 6;            // 0..15
  const int tok0 = blockIdx.x * 64;  // 64 tokens per block
  const int b = blockIdx.x >> 6;     // 64 blocks per batch row

  float ssum = 0.f;
  float cnt = 0.f;

  for (int i = 0; i < 4; ++i) {
    const int tok = tok0 + w * 4 + i;
    float v = logits[(size_t)tok * 64 + lane];

    // pass 1: m1/i1 (argmax, tie -> lower index, matching serial scan)
    float m1 = v; int i1 = lane;
#pragma unroll
    for (int o = 32; o; o >>= 1) {
      float ov = __shfl_xor(m1, o, 64);
      int oi = __shfl_xor(i1, o, 64);
      if (ov > m1 || (ov == m1 && oi < i1)) { m1 = ov; i1 = oi; }
    }
    // pass 2: m2/i2
    float v2 = (lane == i1) ? -3e38f : v;
    float m2 = v2; int i2 = lane;
#pragma unroll
    for (int o = 32; o; o >>= 1) {
      float ov = __shfl_xor(m2, o, 64);
      int oi = __shfl_xor(i2, o, 64);
      if (ov > m2 || (ov == m2 && oi < i2)) { m2 = ov; i2 = oi; }
    }
    // pass 3: m3 (value only)
    float m3 = (lane == i1 || lane == i2) ? -3e38f : v;
#pragma unroll
    for (int o = 32; o; o >>= 1) m3 = fmaxf(m3, __shfl_xor(m3, o, 64));

    // near-tie: exact fp32 re-dot (wave-uniform branch: m's identical on all lanes)
    if ((m1 - m2 < TAU) || (m2 - m3 < TAU)) {
      unsigned long long cand = __ballot(v >= m2 - TAU);
      const float* xr2 = x + (size_t)tok * 2048 + lane * 32;
      while (cand) {
        int e = __ffsll(cand) - 1;
        cand &= cand - 1;
        const float* wr = Wf + (size_t)e * 2048 + lane * 32;
        float s = 0.f;
#pragma unroll
        for (int kk = 0; kk < 32; kk += 8) {
          float4 u0 = *(const float4*)(xr2 + kk);
          float4 w0 = *(const float4*)(wr + kk);
          float4 u1 = *(const float4*)(xr2 + kk + 4);
          float4 w1 = *(const float4*)(wr + kk + 4);
          s += u0.x * w0.x + u0.y * w0.y + u0.z * w0.z + u0.w * w0.w +
               u1.x * w1.x + u1.y * w1.y + u1.z * w1.z + u1.w * w1.w;
        }
#pragma unroll
        for (int o = 32; o; o >>= 1) s += __shfl_xor(s, o, 64);
        if (lane == e) v = s;  // butterfly gave all lanes the sum
      }
      // redo top-2 on corrected values
      m1 = v; i1 = lane;
#pragma unroll
      for (int o = 32; o; o >>= 1) {
        float ov = __shfl_xor(m1, o, 64);
        int oi = __shfl_xor(i1, o, 64);
        if (ov > m1 || (ov == m1 && oi < i1)) { m1 = ov; i1 = oi; }
      }
      v2 = (lane == i1) ? -3e38f : v;
      m2 = v2; i2 = lane;
#pragma unroll
      for (int o = 32; o; o >>= 1) {
        float ov = __shfl_xor(m2, o, 64);
        int oi = __shfl_xor(i2, o, 64);
        if (ov > m2 || (ov == m2 && oi < i2)) { m2 = ov; i2 = oi; }
      }
    }

    // softmax pieces
    float ez = __expf(v - m1);
    float Z = ez;
#pragma unroll
    for (int o = 32; o; o >>= 1) Z += __shfl_xor(Z, o, 64);
    float iz = 1.f / Z;
    float p1 = iz;                   // exp(m1-m1)*iz
    float p2 = __expf(m2 - m1) * iz;
    float dn = 1.f / (p1 + p2 + 1e-20f);
    if (lane == 0) {
      size_t tg = (size_t)tok;
      out[tg * 2 + 0] = (float)i1;
      out[tg * 2 + 1] = (float)i2;
      out[32768 + tg * 2 + 0] = p1 * dn;
      out[32768 + tg * 2 + 1] = p2 * dn;
    }
    ssum += ez * iz;                      // per-(b, expert=lane) softmax sum
    cnt += (float)((lane == i1) + (lane == i2));
  }

  sm[w][lane] = ssum;
  cn[w][lane] = cnt;
  __syncthreads();

  if (tid < 64) {  // wave 0: cross-wave reduce + one atomic per expert
    float s = 0.f, c = 0.f;
#pragma unroll
    for (int ww = 0; ww < 16; ++ww) { s += sm[ww][tid]; c += cn[ww][tid]; }
    atomicAdd(&accum[b * 64 + tid], s);
    atomicAdd(&accum[256 + b * 64 + tid], c);

    // last block finalizes aux loss
    __threadfence();
    unsigned old = 0;
    if (tid == 0) old = atomicAdd((unsigned*)accum + 512, 1u);
    old = (unsigned)__shfl((int)old, 0, 64);
    if (old == 255u) {
      __threadfence();
      float tot = 0.f;
#pragma unroll
      for (int bb = 0; bb < 4; ++bb) {
        float ss = atomicAdd(&accum[bb * 64 + tid], 0.f);
        float cc = atomicAdd(&accum[256 + bb * 64 + tid], 0.f);
        tot += cc * (1.f / 128.f) * (ss * (1.f / 4096.f));
      }
#pragma unroll
      for (int o = 32; o; o >>= 1) tot += __shfl_xor(tot, o, 64);
      if (tid == 0) out[65536] = 0.025f * tot;  // alpha/B = 0.1/4
    }
  }
}

extern "C" void kernel_launch(void* const* d_in, const int* in_sizes, int n_in,
                              void* d_out, int out_size, void* d_ws, size_t ws_size,
                              hipStream_t stream) {
  const float* x = (const float*)d_in[0];
  const float* Wf = (const float*)d_in[1];
  float* out = (float*)d_out;
  unsigned short* Wswz = (unsigned short*)d_ws;
  float* logits = (float*)((char*)d_ws + LOGITS_OFF);
  float* accum = (float*)((char*)d_ws + ACCUM_OFF);
  wconv<<<64, 256, 0, stream>>>(Wf, Wswz, accum);
  gate_gemm<<<1024, 512, 0, stream>>>(x, Wswz, logits);
  gate_top<<<256, 1024, 0, stream>>>(x, Wf, logits, out, accum);
}

// Round 3
// 218.282 us; speedup vs baseline: 1.1231x; 1.0155x over previous
//
#include <hip/hip_runtime.h>

#define TAU 8e-3f

typedef __attribute__((ext_vector_type(8))) short bf16x8;
typedef __attribute__((ext_vector_type(4))) float f32x4;
typedef __attribute__((ext_vector_type(4))) unsigned int u32x4;

// ws layout: Wswz[4*64*64*8 u16 = 256 KB] | logits[16384*64 f32 = 4 MB] | accum[512 f32] | counter[u32]
#define LOGITS_OFF 262144
#define ACCUM_OFF (262144 + 4194304)

// round-to-nearest-even fp32 -> bf16 (as u16)
#define RNE16(f) \
  ((unsigned short)((__float_as_uint(f) + 0x7fffu + ((__float_as_uint(f) >> 16) & 1u)) >> 16))

#define CVTPK(dst, a, b) \
  asm("v_cvt_pk_bf16_f32 %0, %1, %2" : "=v"(dst) : "v"(a), "v"(b))

// async global->LDS, 16 bytes per lane
#define GL16(gp, lp)                                                          \
  __builtin_amdgcn_global_load_lds(                                           \
      (const __attribute__((address_space(1))) unsigned int*)(gp),            \
      (__attribute__((address_space(3))) unsigned int*)(lp), 16, 0, 0)

// ---- kernel 0: W fp32 -> bf16, swizzled to MFMA-fragment-linear ----------
// Wswz[g][ks][lane] (8 u16 each): lane(fm,kg) holds W[g*16+fm][ks*32+kg*8 .. +8]
__global__ __launch_bounds__(256) void wconv(const float* __restrict__ W,
                                             unsigned short* __restrict__ Wswz,
                                             float* __restrict__ accum) {
  int t = blockIdx.x * 256 + threadIdx.x;  // 64 blocks -> 16384 threads
  int g = t >> 12, rem = t & 4095;
  int ks = rem >> 6, lane = rem & 63;
  int fm = lane & 15, kg = lane >> 4;
  const float* src = W + (size_t)(g * 16 + fm) * 2048 + ks * 32 + kg * 8;
  float4 a = *(const float4*)src;
  float4 b = *(const float4*)(src + 4);
  ushort4 lo = make_ushort4(RNE16(a.x), RNE16(a.y), RNE16(a.z), RNE16(a.w));
  ushort4 hi = make_ushort4(RNE16(b.x), RNE16(b.y), RNE16(b.z), RNE16(b.w));
  unsigned short* dst = Wswz + (size_t)t * 8;
  *(ushort4*)dst = lo;
  *(ushort4*)(dst + 4) = hi;
  if (blockIdx.x == 0) {
    accum[threadIdx.x] = 0.f;
    accum[256 + threadIdx.x] = 0.f;
    if (threadIdx.x == 0) ((unsigned*)accum)[512] = 0u;
  }
}

// ---- kernel 1: GEMM via global_load_lds double-buffered staging ----------
// 1024 blocks x 256 threads (4 waves). Block: 16 tokens. Wave w: experts
// [w*16, w*16+16), FULL K=2048 -> one f32x4 accumulator, no cross-wave reduce.
// K-loop: 16 steps of BK=128. x-tile [16 tok][128 K] fp32 = 8 KB, 2 buffers.
// LDS chunk swizzle (16B granules): logical q = p ^ ((p>>5)&7) (involution).
// Stage source uses inverse swizzle; ds_read applies same XOR -> balanced banks.
__global__ __launch_bounds__(256, 4) void gate_gemm(
    const float* __restrict__ x, const unsigned short* __restrict__ Wswz,
    float* __restrict__ logits) {
  __shared__ float __attribute__((aligned(16))) xlds[2][2048];

  const int tid = threadIdx.x;
  const int lane = tid & 63;
  const int w = __builtin_amdgcn_readfirstlane(tid >> 6);  // expert group 0..3
  const int fm = lane & 15;
  const int kg = lane >> 4;
  const int tok0 = blockIdx.x * 16;

  // staging: thread covers dest chunks p0 = tid, p1 = 256 + tid (16 B each)
  const float* src0;
  const float* src1;
  {
    int p0 = tid, q0 = p0 ^ ((p0 >> 5) & 7);
    int p1 = 256 + tid, q1 = p1 ^ ((p1 >> 5) & 7);
    src0 = x + (size_t)(tok0 + (q0 >> 5)) * 2048 + (q0 & 31) * 4;
    src1 = x + (size_t)(tok0 + (q1 >> 5)) * 2048 + (q1 & 31) * 4;
  }
  float* lds_d0 = &xlds[0][tid * 4];
  float* lds_d1 = &xlds[0][1024 + tid * 4];

  // ds_read bases (byte offsets, swizzled), + ks*128 + buf*8192 at use site
  const char* lb0 = (const char*)xlds + fm * 512 + (((kg * 2 + 0) ^ (fm & 7)) * 16);
  const char* lb1 = (const char*)xlds + fm * 512 + (((kg * 2 + 1) ^ (fm & 7)) * 16);

  const bf16x8* wsw = (const bf16x8*)Wswz + lane;  // + (g*64 + absks)*64

  f32x4 acc = (f32x4){0.f, 0.f, 0.f, 0.f};

#define STEP(BUF, S, DO_STAGE)                                               \
  {                                                                          \
    bf16x8 b0 = wsw[(w * 64 + (S) * 4 + 0) * 64];                            \
    bf16x8 b1 = wsw[(w * 64 + (S) * 4 + 1) * 64];                            \
    bf16x8 b2 = wsw[(w * 64 + (S) * 4 + 2) * 64];                            \
    bf16x8 b3 = wsw[(w * 64 + (S) * 4 + 3) * 64];                            \
    if (DO_STAGE) {                                                          \
      GL16(src0 + ((S) + 1) * 128, lds_d0 + (1 - (BUF)) * 2048);             \
      GL16(src1 + ((S) + 1) * 128, lds_d1 + (1 - (BUF)) * 2048);             \
    }                                                                        \
    _Pragma("unroll")                                                        \
    for (int ks = 0; ks < 4; ++ks) {                                         \
      float4 lo = *(const float4*)(lb0 + (BUF)*8192 + ks * 128);             \
      float4 hi = *(const float4*)(lb1 + (BUF)*8192 + ks * 128);             \
      unsigned u0, u1, u2, u3;                                               \
      CVTPK(u0, lo.x, lo.y);                                                 \
      CVTPK(u1, lo.z, lo.w);                                                 \
      CVTPK(u2, hi.x, hi.y);                                                 \
      CVTPK(u3, hi.z, hi.w);                                                 \
      u32x4 uu = (u32x4){u0, u1, u2, u3};                                    \
      bf16x8 a = __builtin_bit_cast(bf16x8, uu);                             \
      bf16x8 bb = (ks == 0) ? b0 : (ks == 1) ? b1 : (ks == 2) ? b2 : b3;     \
      acc = __builtin_amdgcn_mfma_f32_16x16x32_bf16(a, bb, acc, 0, 0, 0);    \
    }                                                                        \
    __syncthreads();                                                         \
  }

  // prologue: stage step 0 into buf 0
  GL16(src0, lds_d0);
  GL16(src1, lds_d1);
  __syncthreads();

#pragma unroll 1
  for (int s = 0; s < 14; s += 2) {
    STEP(0, s, true)
    STEP(1, s + 1, true)
  }
  STEP(0, 14, true)
  STEP(1, 15, false)
#undef STEP

  // C layout: token = kg*4 + r, expert = w*16 + fm
#pragma unroll
  for (int r = 0; r < 4; ++r)
    logits[(size_t)(tok0 + kg * 4 + r) * 64 + w * 16 + fm] = acc[r];
}

// ---- kernel 2: wave-parallel epilogue ------------------------------------
// 256 blocks x 1024 threads (16 waves). Block: 64 tokens; wave: 4 tokens.
// lane = expert. All reductions via shfl butterflies (no serial lane scans).
__global__ __launch_bounds__(1024) void gate_top(
    const float* __restrict__ x, const float* __restrict__ Wf,
    const float* __restrict__ logits, float* __restrict__ out,
    float* __restrict__ accum) {
  __shared__ float sm[16][64];
  __shared__ float cn[16][64];

  const int tid = threadIdx.x;
  const int lane = tid & 63;
  const int w = tid >> 6;            // 0..15
  const int tok0 = blockIdx.x * 64;  // 64 tokens per block
  const int b = blockIdx.x >> 6;     // 64 blocks per batch row

  float ssum = 0.f;
  float cnt = 0.f;

  for (int i = 0; i < 4; ++i) {
    const int tok = tok0 + w * 4 + i;
    float v = logits[(size_t)tok * 64 + lane];

    // pass 1: m1/i1 (argmax, tie -> lower index, matching serial scan)
    float m1 = v; int i1 = lane;
#pragma unroll
    for (int o = 32; o; o >>= 1) {
      float ov = __shfl_xor(m1, o, 64);
      int oi = __shfl_xor(i1, o, 64);
      if (ov > m1 || (ov == m1 && oi < i1)) { m1 = ov; i1 = oi; }
    }
    // pass 2: m2/i2
    float v2 = (lane == i1) ? -3e38f : v;
    float m2 = v2; int i2 = lane;
#pragma unroll
    for (int o = 32; o; o >>= 1) {
      float ov = __shfl_xor(m2, o, 64);
      int oi = __shfl_xor(i2, o, 64);
      if (ov > m2 || (ov == m2 && oi < i2)) { m2 = ov; i2 = oi; }
    }
    // pass 3: m3 (value only)
    float m3 = (lane == i1 || lane == i2) ? -3e38f : v;
#pragma unroll
    for (int o = 32; o; o >>= 1) m3 = fmaxf(m3, __shfl_xor(m3, o, 64));

    // near-tie: exact fp32 re-dot (wave-uniform branch: m's identical on all lanes)
    if ((m1 - m2 < TAU) || (m2 - m3 < TAU)) {
      unsigned long long cand = __ballot(v >= m2 - TAU);
      const float* xr2 = x + (size_t)tok * 2048 + lane * 32;
      while (cand) {
        int e = __ffsll(cand) - 1;
        cand &= cand - 1;
        const float* wr = Wf + (size_t)e * 2048 + lane * 32;
        float s = 0.f;
#pragma unroll
        for (int kk = 0; kk < 32; kk += 8) {
          float4 u0 = *(const float4*)(xr2 + kk);
          float4 w0 = *(const float4*)(wr + kk);
          float4 u1 = *(const float4*)(xr2 + kk + 4);
          float4 w1 = *(const float4*)(wr + kk + 4);
          s += u0.x * w0.x + u0.y * w0.y + u0.z * w0.z + u0.w * w0.w +
               u1.x * w1.x + u1.y * w1.y + u1.z * w1.z + u1.w * w1.w;
        }
#pragma unroll
        for (int o = 32; o; o >>= 1) s += __shfl_xor(s, o, 64);
        if (lane == e) v = s;  // butterfly gave all lanes the sum
      }
      // redo top-2 on corrected values
      m1 = v; i1 = lane;
#pragma unroll
      for (int o = 32; o; o >>= 1) {
        float ov = __shfl_xor(m1, o, 64);
        int oi = __shfl_xor(i1, o, 64);
        if (ov > m1 || (ov == m1 && oi < i1)) { m1 = ov; i1 = oi; }
      }
      v2 = (lane == i1) ? -3e38f : v;
      m2 = v2; i2 = lane;
#pragma unroll
      for (int o = 32; o; o >>= 1) {
        float ov = __shfl_xor(m2, o, 64);
        int oi = __shfl_xor(i2, o, 64);
        if (ov > m2 || (ov == m2 && oi < i2)) { m2 = ov; i2 = oi; }
      }
    }

    // softmax pieces
    float ez = __expf(v - m1);
    float Z = ez;
#pragma unroll
    for (int o = 32; o; o >>= 1) Z += __shfl_xor(Z, o, 64);
    float iz = 1.f / Z;
    float p1 = iz;                   // exp(m1-m1)*iz
    float p2 = __expf(m2 - m1) * iz;
    float dn = 1.f / (p1 + p2 + 1e-20f);
    if (lane == 0) {
      size_t tg = (size_t)tok;
      out[tg * 2 + 0] = (float)i1;
      out[tg * 2 + 1] = (float)i2;
      out[32768 + tg * 2 + 0] = p1 * dn;
      out[32768 + tg * 2 + 1] = p2 * dn;
    }
    ssum += ez * iz;                      // per-(b, expert=lane) softmax sum
    cnt += (float)((lane == i1) + (lane == i2));
  }

  sm[w][lane] = ssum;
  cn[w][lane] = cnt;
  __syncthreads();

  if (tid < 64) {  // wave 0: cross-wave reduce + one atomic per expert
    float s = 0.f, c = 0.f;
#pragma unroll
    for (int ww = 0; ww < 16; ++ww) { s += sm[ww][tid]; c += cn[ww][tid]; }
    atomicAdd(&accum[b * 64 + tid], s);
    atomicAdd(&accum[256 + b * 64 + tid], c);

    // last block finalizes aux loss
    __threadfence();
    unsigned old = 0;
    if (tid == 0) old = atomicAdd((unsigned*)accum + 512, 1u);
    old = (unsigned)__shfl((int)old, 0, 64);
    if (old == 255u) {
      __threadfence();
      float tot = 0.f;
#pragma unroll
      for (int bb = 0; bb < 4; ++bb) {
        float ss = atomicAdd(&accum[bb * 64 + tid], 0.f);
        float cc = atomicAdd(&accum[256 + bb * 64 + tid], 0.f);
        tot += cc * (1.f / 128.f) * (ss * (1.f / 4096.f));
      }
#pragma unroll
      for (int o = 32; o; o >>= 1) tot += __shfl_xor(tot, o, 64);
      if (tid == 0) out[65536] = 0.025f * tot;  // alpha/B = 0.1/4
    }
  }
}

extern "C" void kernel_launch(void* const* d_in, const int* in_sizes, int n_in,
                              void* d_out, int out_size, void* d_ws, size_t ws_size,
                              hipStream_t stream) {
  const float* x = (const float*)d_in[0];
  const float* Wf = (const float*)d_in[1];
  float* out = (float*)d_out;
  unsigned short* Wswz = (unsigned short*)d_ws;
  float* logits = (float*)((char*)d_ws + LOGITS_OFF);
  float* accum = (float*)((char*)d_ws + ACCUM_OFF);
  wconv<<<64, 256, 0, stream>>>(Wf, Wswz, accum);
  gate_gemm<<<1024, 256, 0, stream>>>(x, Wswz, logits);
  gate_top<<<256, 1024, 0, stream>>>(x, Wf, logits, out, accum);
}